// Round 13
// baseline (121.333 us; speedup 1.0000x reference)
//
#include <hip/hip_runtime.h>
#include <cmath>
#include <complex>
#include <algorithm>

#define NBH   32      // histogram blocks
#define NB2   16      // k_tail blocks
#define CAP_S 512     // max edges out of Co (out-degree ~Poisson(12))
#define CAP_T 64      // max distinct targets of Co's edges
#define CAP_M 4096    // max edges whose source is a target of Co
#define EB    64      // per-batch edges staged in LDS in tail kernels
#define HW_MAX 12544  // hist words cap: N <= 50176 (N=50000 here)
#define BM_MAX 1568   // bitmap words cap: N <= 50176

// ====================== host-side Wigner 3j (exact port, runs at .so load) =====================
namespace w3jhost {
static double fact(int n){
  static const double f[13]={1,1,2,6,24,120,720,5040,40320,362880,3628800,39916800,479001600};
  return f[n];
}
static double su2_cg(int j1,int m1,int j2,int m2,int j3,int m3){
  if(m3!=m1+m2) return 0.0;
  int vmin = std::max(std::max(-j1+j2+m3,-j1+m1),0);
  int vmax = std::min(std::min(j2+j3+m1, j3-j1+j2), j3+m3);
  double C = std::sqrt((double)(2*j3+1)*fact(j3+j1-j2)*fact(j3-j1+j2)*fact(j1+j2-j3)*fact(j3+m3)*fact(j3-m3)
            /(fact(j1+j2+j3+1)*fact(j1-m1)*fact(j1+m1)*fact(j2-m2)*fact(j2+m2)));
  double S=0.0;
  for(int v=vmin;v<=vmax;v++){
    double sgn = ((v+j2+m2)&1)?-1.0:1.0;
    S += sgn/fact(v)*fact(j2+j3+m1-v)*fact(j1-m1+v)/fact(j3-j1+j2-v)/fact(j3+m3-v)/fact(v+j1-j2-m3);
  }
  return C*S;
}
static void real_basis(int l, std::complex<double> q[7][7]){
  for(int i=0;i<7;i++)for(int j=0;j<7;j++) q[i][j]=0.0;
  const double r = std::sqrt(0.5);
  for(int m=-l;m<0;m++){ q[l+m][l-m]=r; q[l+m][l+m]=std::complex<double>(0.0,-r); }
  q[l][l]=1.0;
  for(int m=1;m<=l;m++){ double sg=(m&1)?-1.0:1.0; q[l+m][l+m]=sg*r; q[l+m][l-m]=std::complex<double>(0.0,sg*r); }
  std::complex<double> f;
  switch(l&3){ case 0: f={1,0};break; case 1: f={0,-1};break; case 2: f={-1,0};break; default: f={0,1};break; }
  for(int i=0;i<7;i++)for(int j=0;j<7;j++) q[i][j]*=f;
}
} // namespace w3jhost

struct W3JArg { float w[675]; };  // 7 paths concatenated, layout [i*(2l2+1)+j]*5+k

static W3JArg compute_w3j(){
  using namespace w3jhost;
  W3JArg out{};
  const int pl1[7]={0,1,1,2,2,3,3}, pl2[7]={2,1,3,0,2,1,3};
  int off=0;
  for(int p=0;p<7;p++){
    int l1=pl1[p], l2=pl2[p], l3=2;
    int n1=2*l1+1, n2=2*l2+1, n3=2*l3+1;
    double C[7][7][5];
    for(int i=0;i<7;i++)for(int k=0;k<7;k++)for(int n=0;n<5;n++) C[i][k][n]=0.0;
    for(int m1=-l1;m1<=l1;m1++)for(int m2=-l2;m2<=l2;m2++)
      if(std::abs(m1+m2)<=l3) C[l1+m1][l2+m2][l3+m1+m2]=su2_cg(l1,m1,l2,m2,l3,m1+m2);
    std::complex<double> Q1[7][7],Q2[7][7],Q3[7][7];
    real_basis(l1,Q1); real_basis(l2,Q2); real_basis(l3,Q3);
    double Cr[7][7][5]; double nrm=0.0;
    for(int a=0;a<n1;a++)for(int b=0;b<n2;b++)for(int c=0;c<n3;c++){
      std::complex<double> s(0.0,0.0);
      for(int i=0;i<n1;i++)for(int k=0;k<n2;k++)for(int n=0;n<n3;n++){
        double cv=C[i][k][n]; if(cv==0.0) continue;
        s += Q1[i][a]*Q2[k][b]*std::conj(Q3[n][c])*cv;  // einsum 'ij,kl,mn,ikn->jlm'
      }
      Cr[a][b][c]=s.real(); nrm+=s.real()*s.real();
    }
    nrm=std::sqrt(nrm);
    for(int a=0;a<n1;a++)for(int b=0;b<n2;b++)for(int c=0;c<n3;c++)
      out.w[off+(a*n2+b)*n3+c]=(float)(Cr[a][b][c]/nrm);
    off+=n1*n2*n3;
  }
  return out;
}
static const W3JArg g_w3j = compute_w3j();  // constant data; same every call

// ====================== device helpers ======================
__device__ __forceinline__ void calc_sh(float x,float y,float z,float* sh){
  float x2=x*x,y2=y*y,z2=z*z;
  const float s3=1.7320508075688772f, s5=2.2360679774997896f, s15=3.872983346207417f;
  const float s70_4=2.091650066335189f, s105=10.246950765959598f, s42_4=1.6201851746019651f;
  const float s7_2=1.3228756555322954f, s105_2=5.123475382979799f;
  sh[0]=1.f;
  sh[1]=s3*x; sh[2]=s3*y; sh[3]=s3*z;
  sh[4]=s15*x*z; sh[5]=s15*x*y; sh[6]=s5*(y2-0.5f*(x2+z2)); sh[7]=s15*y*z; sh[8]=0.5f*s15*(z2-x2);
  sh[9]=s70_4*x*(3.f*z2-x2); sh[10]=s105*x*y*z; sh[11]=s42_4*x*(5.f*y2-1.f);
  sh[12]=s7_2*y*(5.f*y2-3.f); sh[13]=s42_4*z*(5.f*y2-1.f); sh[14]=s105_2*y*(z2-x2); sh[15]=s70_4*z*(z2-3.f*x2);
}

__device__ __forceinline__ float cloadf(const float* p){ return __hip_atomic_load(p,__ATOMIC_RELAXED,__HIP_MEMORY_SCOPE_AGENT); }

// FENCE-FREE grid barrier (r7: __threadfence cost 137us in wbl2/inv walks; drain-only is enough
// because all cross-block data moves via device-scope atomics).
__device__ __forceinline__ void gridbar(int* ctr,int count){
  __syncthreads();
  if(threadIdx.x==0){
    asm volatile("s_waitcnt vmcnt(0) lgkmcnt(0)" ::: "memory");
    __hip_atomic_fetch_add(ctr,1,__ATOMIC_RELAXED,__HIP_MEMORY_SCOPE_AGENT);
    int it=0;
    while(__hip_atomic_load(ctr,__ATOMIC_RELAXED,__HIP_MEMORY_SCOPE_AGENT)<count){
      if(it<16) __builtin_amdgcn_s_sleep(2);
      else      __builtin_amdgcn_s_sleep(16);
      ++it;
    }
  }
  __syncthreads();
}

// ====================== k1: LDS byte-packed histogram of eto (+ ctrl/nmid zero) ======================
__global__ void __launch_bounds__(1024,1)
k_hist(const int* __restrict__ eto, int E, int N, int* __restrict__ histg,
       int* __restrict__ ctrl /*20 ints: packed(2),numS,numM,bars(8),pad,flag@16*/,
       float* __restrict__ nmid_g){
  __shared__ int hist[HW_MAX];    // 4x8-bit counters/word (max in-degree ~35 << 255)
  const int HW=(N+3)>>2;
  const int tid=threadIdx.x;
  // zero control words + nmid (consumers are all in LATER dispatches — no race)
  if(blockIdx.x==0 && tid<20) ctrl[tid]=0;
  for(int i=blockIdx.x*1024+tid;i<CAP_T*80;i+=NBH*1024) nmid_g[i]=0.f;
  for(int w=tid;w<HW;w+=1024) hist[w]=0;
  __syncthreads();
  int nQ=(E+3)>>2;
  for(int q=blockIdx.x*1024+tid;q<nQ;q+=NBH*1024){
    int e=q*4;
    if(e+3<E){
      int4 v=*reinterpret_cast<const int4*>(eto+e);
      atomicAdd(&hist[v.x>>2], 1<<((v.x&3)*8));
      atomicAdd(&hist[v.y>>2], 1<<((v.y&3)*8));
      atomicAdd(&hist[v.z>>2], 1<<((v.z&3)*8));
      atomicAdd(&hist[v.w>>2], 1<<((v.w&3)*8));
    } else {
      for(;e<E;e++){ int t=eto[e]; atomicAdd(&hist[t>>2], 1<<((t&3)*8)); }
    }
  }
  __syncthreads();
  for(int w=tid;w<HW;w+=1024) histg[blockIdx.x*HW+w]=hist[w];   // coalesced plain stores
}

// ====================== k2: fused argmax (blocks 0..AB-1) + spin + collect (all blocks) ======================
// Argmax needs only ~49 blocks; collect blocks spin on a 49-arrival flag (read-only polls on a
// DIFFERENT cache line than packed), then scan. Saves one dispatch boundary (~3.5us measured).
// Deadlock-free: 586 blocks x 256 thr, ~no LDS -> all co-resident (8 blocks/CU capacity).
__global__ void __launch_bounds__(256,1)
k_collect(const int* __restrict__ histg, const int* __restrict__ efrom, int E, int N,
          unsigned long long* __restrict__ packed, int* __restrict__ flag,
          int* __restrict__ S, int* __restrict__ numS){
  __shared__ int co_s;
  const int tid=threadIdx.x;
  const int HW=(N+3)>>2;
  const int AB=(HW+255)>>8;            // #argmax blocks (49 for N=50000)
  if((int)blockIdx.x<AB){
    int w=blockIdx.x*256+tid;
    unsigned long long lm=0ull;
    if(w<HW){
      int c0=0,c1=0,c2=0,c3=0;
      #pragma unroll
      for(int b=0;b<NBH;b++){
        int h=histg[b*HW+w];           // plain cached loads (prev dispatch), coalesced
        c0+=h&255; c1+=(h>>8)&255; c2+=(h>>16)&255; c3+=(int)((unsigned)h>>24);
      }
      int node=w*4;
      if(c0>0)          lm=max(lm,(((unsigned long long)(unsigned)c0)<<32)|(unsigned long long)(0xFFFFFFFFu-(unsigned)(node  )));
      if(node+1<N&&c1>0)lm=max(lm,(((unsigned long long)(unsigned)c1)<<32)|(unsigned long long)(0xFFFFFFFFu-(unsigned)(node+1)));
      if(node+2<N&&c2>0)lm=max(lm,(((unsigned long long)(unsigned)c2)<<32)|(unsigned long long)(0xFFFFFFFFu-(unsigned)(node+2)));
      if(node+3<N&&c3>0)lm=max(lm,(((unsigned long long)(unsigned)c3)<<32)|(unsigned long long)(0xFFFFFFFFu-(unsigned)(node+3)));
    }
    #pragma unroll
    for(int off=32;off;off>>=1){
      unsigned long long o=__shfl_xor(lm,off);
      lm=max(lm,o);
    }
    if((tid&63)==0 && lm) atomicMax(packed,lm);
    __syncthreads();
    if(tid==0){
      asm volatile("s_waitcnt vmcnt(0) lgkmcnt(0)" ::: "memory");
      __hip_atomic_fetch_add(flag,1,__ATOMIC_RELAXED,__HIP_MEMORY_SCOPE_AGENT);
    }
  }
  if(tid==0){
    int it=0;
    while(__hip_atomic_load(flag,__ATOMIC_RELAXED,__HIP_MEMORY_SCOPE_AGENT)<AB){
      if(it<8) __builtin_amdgcn_s_sleep(2);
      else     __builtin_amdgcn_s_sleep(8);
      ++it;
    }
    unsigned long long pk=__hip_atomic_load(packed,__ATOMIC_RELAXED,__HIP_MEMORY_SCOPE_AGENT);
    co_s=(int)(0xFFFFFFFFu-(unsigned)(pk&0xFFFFFFFFull));  // numpy argmax (first max)
  }
  __syncthreads();
  int co=co_s;
  int q=blockIdx.x*256+tid;
  int e=q*4;
  if(e+3<E){
    int4 v=*reinterpret_cast<const int4*>(efrom+e);
    int f[4]={v.x,v.y,v.z,v.w};
    #pragma unroll
    for(int k=0;k<4;k++){
      if(f[k]==co){
        int p=atomicAdd(numS,1);
        if(p<CAP_S) S[p]=e+k;
      }
    }
  } else {
    for(;e<E;e++){
      if(efrom[e]==co){
        int p=atomicAdd(numS,1);
        if(p<CAP_S) S[p]=e;
      }
    }
  }
}

// ====================== k3: scan efrom for M-edges (bitmap + slot-packed append) ======================
__global__ void __launch_bounds__(256,1)
k_scanM(const int* __restrict__ efrom, const int* __restrict__ eto, int E, int N,
        const int* __restrict__ S, const int* __restrict__ numS,
        int* __restrict__ M, int* __restrict__ numM){
  __shared__ int bitmap[BM_MAX];
  __shared__ int Te[CAP_T];
  __shared__ int Tlist[CAP_T];
  __shared__ int nTs;
  const int tid=threadIdx.x;
  int ns=*numS; if(ns>CAP_S) ns=CAP_S;
  int nsc=min(ns,CAP_T);
  const int BMW=(N+31)>>5;
  for(int w=tid;w<BMW;w+=256) bitmap[w]=0;
  if(tid<nsc) Te[tid]=eto[S[tid]];
  __syncthreads();
  if(tid<64){   // wave 0: deterministic ballot dedup + prefix slots (same order as k_tail)
    bool keep=false; int myv=0;
    if(tid<nsc){
      myv=Te[tid];
      keep=true;
      for(int k=0;k<tid;k++) if(Te[k]==myv){ keep=false; break; }
    }
    unsigned long long mask=__ballot(keep);
    if(keep){
      int slot=__popcll(mask&((1ull<<tid)-1ull));
      Tlist[slot]=myv;
    }
    if(tid==0) nTs=__popcll(mask);
  }
  __syncthreads();
  int nT=nTs;
  if(tid<nT){ int v=Tlist[tid]; atomicOr(&bitmap[v>>5], 1<<(v&31)); }
  __syncthreads();
  int q=blockIdx.x*256+tid;
  int e=q*4;
  if(e+3<E){
    int4 v=*reinterpret_cast<const int4*>(efrom+e);
    int f[4]={v.x,v.y,v.z,v.w};
    #pragma unroll
    for(int k=0;k<4;k++){
      int s=f[k];
      if((bitmap[s>>5]>>(s&31))&1){
        int sl=0;
        for(int kk=0;kk<nT;kk++) if(Tlist[kk]==s){ sl=kk; break; }
        int p=atomicAdd(numM,1);
        if(p<CAP_M) M[p]=(e+k)|(sl<<20);   // e < 2^20 (E=600k); slot in bits 20..25
      }
    }
  } else {
    for(;e<E;e++){
      int s=efrom[e];
      if((bitmap[s>>5]>>(s&31))&1){
        int sl=0;
        for(int kk=0;kk<nT;kk++) if(Tlist[kk]==s){ sl=kk; break; }
        int p=atomicAdd(numM,1);
        if(p<CAP_M) M[p]=e|(sl<<20);
      }
    }
  }
}

// ====================== k_tail: mlp (16 blocks) -> gridbar -> final (block 0) ======================
__global__ void __launch_bounds__(1024,1)
k_tail(const float* __restrict__ x, const float* __restrict__ pos,
       const int* __restrict__ efrom, const int* __restrict__ eto,
       const float* __restrict__ W1, const float* __restrict__ W2,
       const float* __restrict__ tp2,
       const int* __restrict__ S, const int* __restrict__ numS,
       const int* __restrict__ M, const int* __restrict__ numM,
       float* __restrict__ nmid_g, int* __restrict__ bars,
       W3JArg w3, float* __restrict__ out5){
  __shared__ float W1s[600], W2s[600];
  __shared__ float shs[EB*16], embs[EB*20], hs[EB*30], tws[EB*20];
  __shared__ float es_[EB], dd_[EB];
  __shared__ int   sl_[EB];
  __shared__ float w3s[675], nmid_s[CAP_T*80], tp2s[35], acc[5];
  __shared__ int   Te[CAP_T], Tlist[CAP_T], nTs;
  const int tid=threadIdx.x, bid=blockIdx.x;

  // ---- phase 1: per-M-edge radial MLP + sh -> nmid (task-parallel pipeline, all blocks) ----
  int nm=*numM; if(nm>CAP_M) nm=CAP_M;     // plain: crosses dispatch boundary only
  for(int i=tid;i<600;i+=1024){ W1s[i]=W1[i]; W2s[i]=W2[i]; }
  int per=(nm+NB2-1)/NB2;
  int lo=min(nm,bid*per), hi=min(nm,lo+per);
  for(int base=lo;base<hi;base+=EB){
    int cnt=min(EB,hi-base);
    __syncthreads();            // W1s ready (1st iter) + LDS reuse across batches
    if(tid<cnt){
      int m=M[base+tid];
      int e=m&0xFFFFF, sl=m>>20;
      sl_[tid]=sl;
      int a=efrom[e], b=eto[e];
      float dx=pos[3*b]-pos[3*a], dy=pos[3*b+1]-pos[3*a+1], dz=pos[3*b+2]-pos[3*a+2];
      float d=sqrtf(dx*dx+dy*dy+dz*dz);
      float inv=1.f/d;
      calc_sh(dx*inv,dy*inv,dz*inv,&shs[tid*16]);
      dd_[tid]=d;
      es_[tid]=x[b]*(0.18257418583505536f*0.4082482904638631f); // 1/sqrt30 * 1/sqrt6
    }
    __syncthreads();
    for(int t=tid;t<cnt*20;t+=1024){      // radial embedding
      int ee=t/20, i=t-ee*20;
      const float inv_step=21.f/3.5f;
      const float pref=(float)(1.14136*7.3890560989306495);  // 1.14136*e^2
      float di=dd_[ee]*inv_step;
      float A=di-(float)i, B=(float)(i+2)-di;
      float ua=(A>0.f)?expf(-1.f/A):0.f;
      float ub=(B>0.f)?expf(-1.f/B):0.f;
      embs[ee*20+i]=pref*ua*ub;
    }
    __syncthreads();
    for(int t=tid;t<cnt*30;t+=1024){      // MLP layer 1
      int ee=t/30, j=t-ee*30;
      float z=0.f;
      #pragma unroll
      for(int i=0;i<20;i++) z+=embs[ee*20+i]*W1s[i*30+j];
      z*=0.22360679774997896f;                  // 1/sqrt20
      hs[ee*30+j]=1.679177f*z/(1.f+expf(-z));   // NORM2MOM * silu
    }
    __syncthreads();
    for(int t=tid;t<cnt*20;t+=1024){      // MLP layer 2
      int ee=t/20, c=t-ee*20;
      float v=0.f;
      #pragma unroll
      for(int j=0;j<30;j++) v+=hs[ee*30+j]*W2s[j*20+c];
      tws[ee*20+c]=v;
    }
    __syncthreads();
    for(int t=tid;t<cnt*80;t+=1024){      // mid accumulation (device-scope atomics = coherent)
      int ee=t/80, oo=t-ee*80;
      int sl=sl_[ee];
      int l,u,mm;
      if(oo<5){ l=0; u=oo; mm=0; }
      else if(oo<20){ int r=oo-5;  l=1; u=r/3; mm=r-u*3; }
      else if(oo<45){ int r=oo-20; l=2; u=r/5; mm=r-u*5; }
      else          { int r=oo-45; l=3; u=r/7; mm=r-u*7; }
      float val=es_[ee]*tws[ee*20+l*5+u]*shs[ee*16+l*l+mm];
      atomicAdd(&nmid_g[sl*80+oo],val);
    }
  }
  gridbar(&bars[0],NB2);
  if(bid!=0) return;

  // ---- phase 2: second tensor product + output (block 0 only) ----
  for(int i=tid;i<675;i+=1024) w3s[i]=w3.w[i];
  if(tid<35) tp2s[tid]=tp2[tid];
  if(tid<5) acc[tid]=0.f;
  int ns=*numS; if(ns>CAP_S) ns=CAP_S;
  int nsc=min(ns,CAP_T);
  if(tid<nsc) Te[tid]=eto[S[tid]];
  __syncthreads();
  if(tid<64){   // identical dedup order as k_scanM -> identical slots
    bool keep=false; int myv=0;
    if(tid<nsc){
      myv=Te[tid];
      keep=true;
      for(int k=0;k<tid;k++) if(Te[k]==myv){ keep=false; break; }
    }
    unsigned long long mask=__ballot(keep);
    if(keep){
      int slot=__popcll(mask&((1ull<<tid)-1ull));
      Tlist[slot]=myv;
    }
    if(tid==0) nTs=__popcll(mask);
  }
  __syncthreads();
  int nT=nTs;
  for(int i=tid;i<nT*80;i+=1024) nmid_s[i]=cloadf(&nmid_g[i]);  // coherent: written pre-barrier by other blocks
  for(int base=0;base<ns;base+=EB){
    int cnt=min(EB,ns-base);
    __syncthreads();
    if(tid<cnt){
      int e=S[base+tid];
      int a=efrom[e], b=eto[e];
      int sl=-1;
      for(int k=0;k<nT;k++) if(Tlist[k]==b){ sl=k; break; }
      sl_[tid]=sl;
      if(sl>=0){
        float dx=pos[3*b]-pos[3*a], dy=pos[3*b+1]-pos[3*a+1], dz=pos[3*b+2]-pos[3*a+2];
        float d=sqrtf(dx*dx+dy*dy+dz*dz);
        float inv=1.f/d;
        calc_sh(dx*inv,dy*inv,dz*inv,&shs[tid*16]);
      }
    }
    __syncthreads();
    for(int t=tid;t<cnt*35;t+=1024){
      int ee=t/35, r=t-ee*35, p=r/5, u=r-p*5;
      int sl=sl_[ee];
      if(sl>=0){
        int l1=(p+1)>>1;                         // 0,1,1,2,2,3,3
        int l2=(0x3636>>(2*p))&3;                // 2,1,3,0,2,1,3
        const unsigned long long wbpack=
          (25ULL<<9)|(70ULL<<18)|(175ULL<<27)|(200ULL<<36)|(325ULL<<45)|(430ULL<<54);
        int wb=(int)((wbpack>>(9*p))&511ULL);    // 0,25,70,175,200,325,430
        int n1=2*l1+1, n2=2*l2+1;
        float tu=tp2s[p*5+u];
        float o0=0.f,o1=0.f,o2=0.f,o3=0.f,o4=0.f;
        const float* mrow=&nmid_s[sl*80+5*l1*l1+u*n1];
        const float* shrow=&shs[ee*16+l2*l2];
        const float* Wp=&w3s[wb];
        for(int i=0;i<n1;i++){
          float mi=mrow[i]*tu;
          for(int j=0;j<n2;j++){
            float c=mi*shrow[j];
            const float* Wk=Wp+(i*n2+j)*5;
            o0+=Wk[0]*c; o1+=Wk[1]*c; o2+=Wk[2]*c; o3+=Wk[3]*c; o4+=Wk[4]*c;
          }
        }
        atomicAdd(&acc[0],o0); atomicAdd(&acc[1],o1); atomicAdd(&acc[2],o2);
        atomicAdd(&acc[3],o3); atomicAdd(&acc[4],o4);
      }
    }
    __syncthreads();
  }
  __syncthreads();
  const float scale=0.37796447300922725f*0.4082482904638631f;  // ALPHA2 * 1/sqrt(6)
  if(tid<5) out5[tid]=acc[tid]*scale;
}

// ====================== launch ======================
extern "C" void kernel_launch(void* const* d_in, const int* in_sizes, int n_in,
                              void* d_out, int out_size, void* d_ws, size_t ws_size,
                              hipStream_t stream){
  const float* x    =(const float*)d_in[0];
  const float* pos  =(const float*)d_in[1];
  const int*   efrom=(const int*)  d_in[2];
  const int*   eto  =(const int*)  d_in[3];
  const float* W1   =(const float*)d_in[4];
  const float* W2   =(const float*)d_in[5];
  const float* tp2  =(const float*)d_in[6];
  int N=in_sizes[0], E=in_sizes[2];
  int HW=(N+3)>>2;

  char* ws=(char*)d_ws;
  size_t o=0;
  int* ctrl=(int*)(ws+o);                   // 20 ints zeroed in k_hist
  unsigned long long* packed=(unsigned long long*)(ws+o); o+=8;
  int* numS=(int*)(ws+o);                   o+=4;
  int* numM=(int*)(ws+o);                   o+=4;
  int* bars=(int*)(ws+o);                   o+=8*4;
  o=(o+63)&~(size_t)63;                     // flag on its own cache line (poll traffic off packed's line)
  int* flag=(int*)(ws+o);                   o+=4;
  o=(o+63)&~(size_t)63;
  int* histg=(int*)(ws+o);                  o+=(size_t)NBH*HW*4;   // 1.6 MB, fully overwritten by k1
  int* S=(int*)(ws+o);                      o+=(size_t)CAP_S*4;
  int* M=(int*)(ws+o);                      o+=(size_t)CAP_M*4;
  float* nmid_g=(float*)(ws+o);             o+=(size_t)CAP_T*80*4; // zeroed in k_hist

  int nQ=(E+3)>>2;
  int gScan=(nQ+255)/256;
  k_hist   <<<NBH,1024,0,stream>>>(eto,E,N,histg,ctrl,nmid_g);
  k_collect<<<gScan,256,0,stream>>>(histg,efrom,E,N,packed,flag,S,numS);
  k_scanM  <<<gScan,256,0,stream>>>(efrom,eto,E,N,S,numS,M,numM);
  k_tail   <<<NB2,1024,0,stream>>>(x,pos,efrom,eto,W1,W2,tp2,S,numS,M,numM,nmid_g,bars,g_w3j,(float*)d_out);
}

// Round 14
// 110.694 us; speedup vs baseline: 1.0961x; 1.0961x over previous
//
#include <hip/hip_runtime.h>
#include <cmath>
#include <complex>
#include <algorithm>

#define NBH   32      // histogram blocks
#define NB2   16      // k_tail blocks
#define CAP_S 512     // max edges out of Co (out-degree ~Poisson(12))
#define CAP_T 64      // max distinct targets of Co's edges
#define CAP_M 4096    // max edges whose source is a target of Co
#define EB    64      // per-batch edges staged in LDS in tail kernels
#define HW_MAX 12544  // hist words cap: N <= 50176 (N=50000 here)
#define BM_MAX 1568   // bitmap words cap: N <= 50176

// ====================== host-side Wigner 3j (exact port, runs at .so load) =====================
namespace w3jhost {
static double fact(int n){
  static const double f[13]={1,1,2,6,24,120,720,5040,40320,362880,3628800,39916800,479001600};
  return f[n];
}
static double su2_cg(int j1,int m1,int j2,int m2,int j3,int m3){
  if(m3!=m1+m2) return 0.0;
  int vmin = std::max(std::max(-j1+j2+m3,-j1+m1),0);
  int vmax = std::min(std::min(j2+j3+m1, j3-j1+j2), j3+m3);
  double C = std::sqrt((double)(2*j3+1)*fact(j3+j1-j2)*fact(j3-j1+j2)*fact(j1+j2-j3)*fact(j3+m3)*fact(j3-m3)
            /(fact(j1+j2+j3+1)*fact(j1-m1)*fact(j1+m1)*fact(j2-m2)*fact(j2+m2)));
  double S=0.0;
  for(int v=vmin;v<=vmax;v++){
    double sgn = ((v+j2+m2)&1)?-1.0:1.0;
    S += sgn/fact(v)*fact(j2+j3+m1-v)*fact(j1-m1+v)/fact(j3-j1+j2-v)/fact(j3+m3-v)/fact(v+j1-j2-m3);
  }
  return C*S;
}
static void real_basis(int l, std::complex<double> q[7][7]){
  for(int i=0;i<7;i++)for(int j=0;j<7;j++) q[i][j]=0.0;
  const double r = std::sqrt(0.5);
  for(int m=-l;m<0;m++){ q[l+m][l-m]=r; q[l+m][l+m]=std::complex<double>(0.0,-r); }
  q[l][l]=1.0;
  for(int m=1;m<=l;m++){ double sg=(m&1)?-1.0:1.0; q[l+m][l+m]=sg*r; q[l+m][l-m]=std::complex<double>(0.0,sg*r); }
  std::complex<double> f;
  switch(l&3){ case 0: f={1,0};break; case 1: f={0,-1};break; case 2: f={-1,0};break; default: f={0,1};break; }
  for(int i=0;i<7;i++)for(int j=0;j<7;j++) q[i][j]*=f;
}
} // namespace w3jhost

struct W3JArg { float w[675]; };  // 7 paths concatenated, layout [i*(2l2+1)+j]*5+k

static W3JArg compute_w3j(){
  using namespace w3jhost;
  W3JArg out{};
  const int pl1[7]={0,1,1,2,2,3,3}, pl2[7]={2,1,3,0,2,1,3};
  int off=0;
  for(int p=0;p<7;p++){
    int l1=pl1[p], l2=pl2[p], l3=2;
    int n1=2*l1+1, n2=2*l2+1, n3=2*l3+1;
    double C[7][7][5];
    for(int i=0;i<7;i++)for(int k=0;k<7;k++)for(int n=0;n<5;n++) C[i][k][n]=0.0;
    for(int m1=-l1;m1<=l1;m1++)for(int m2=-l2;m2<=l2;m2++)
      if(std::abs(m1+m2)<=l3) C[l1+m1][l2+m2][l3+m1+m2]=su2_cg(l1,m1,l2,m2,l3,m1+m2);
    std::complex<double> Q1[7][7],Q2[7][7],Q3[7][7];
    real_basis(l1,Q1); real_basis(l2,Q2); real_basis(l3,Q3);
    double Cr[7][7][5]; double nrm=0.0;
    for(int a=0;a<n1;a++)for(int b=0;b<n2;b++)for(int c=0;c<n3;c++){
      std::complex<double> s(0.0,0.0);
      for(int i=0;i<n1;i++)for(int k=0;k<n2;k++)for(int n=0;n<n3;n++){
        double cv=C[i][k][n]; if(cv==0.0) continue;
        s += Q1[i][a]*Q2[k][b]*std::conj(Q3[n][c])*cv;  // einsum 'ij,kl,mn,ikn->jlm'
      }
      Cr[a][b][c]=s.real(); nrm+=s.real()*s.real();
    }
    nrm=std::sqrt(nrm);
    for(int a=0;a<n1;a++)for(int b=0;b<n2;b++)for(int c=0;c<n3;c++)
      out.w[off+(a*n2+b)*n3+c]=(float)(Cr[a][b][c]/nrm);
    off+=n1*n2*n3;
  }
  return out;
}
static const W3JArg g_w3j = compute_w3j();  // constant data; same every call

// ====================== device helpers ======================
__device__ __forceinline__ void calc_sh(float x,float y,float z,float* sh){
  float x2=x*x,y2=y*y,z2=z*z;
  const float s3=1.7320508075688772f, s5=2.2360679774997896f, s15=3.872983346207417f;
  const float s70_4=2.091650066335189f, s105=10.246950765959598f, s42_4=1.6201851746019651f;
  const float s7_2=1.3228756555322954f, s105_2=5.123475382979799f;
  sh[0]=1.f;
  sh[1]=s3*x; sh[2]=s3*y; sh[3]=s3*z;
  sh[4]=s15*x*z; sh[5]=s15*x*y; sh[6]=s5*(y2-0.5f*(x2+z2)); sh[7]=s15*y*z; sh[8]=0.5f*s15*(z2-x2);
  sh[9]=s70_4*x*(3.f*z2-x2); sh[10]=s105*x*y*z; sh[11]=s42_4*x*(5.f*y2-1.f);
  sh[12]=s7_2*y*(5.f*y2-3.f); sh[13]=s42_4*z*(5.f*y2-1.f); sh[14]=s105_2*y*(z2-x2); sh[15]=s70_4*z*(z2-3.f*x2);
}

__device__ __forceinline__ float cloadf(const float* p){ return __hip_atomic_load(p,__ATOMIC_RELAXED,__HIP_MEMORY_SCOPE_AGENT); }

// FENCE-FREE grid barrier (r7: __threadfence cost 137us in wbl2/inv walks; drain-only is enough
// because all cross-block data moves via device-scope atomics).
__device__ __forceinline__ void gridbar(int* ctr,int count){
  __syncthreads();
  if(threadIdx.x==0){
    asm volatile("s_waitcnt vmcnt(0) lgkmcnt(0)" ::: "memory");
    __hip_atomic_fetch_add(ctr,1,__ATOMIC_RELAXED,__HIP_MEMORY_SCOPE_AGENT);
    int it=0;
    while(__hip_atomic_load(ctr,__ATOMIC_RELAXED,__HIP_MEMORY_SCOPE_AGENT)<count){
      if(it<16) __builtin_amdgcn_s_sleep(2);
      else      __builtin_amdgcn_s_sleep(16);
      ++it;
    }
  }
  __syncthreads();
}

// ====================== k1: LDS byte-packed histogram of eto (+ ctrl/nmid zero) ======================
__global__ void __launch_bounds__(1024,1)
k_hist(const int* __restrict__ eto, int E, int N, int* __restrict__ histg,
       int* __restrict__ ctrl /*12 ints: packed(2),numS,numM,bars(8)*/,
       float* __restrict__ nmid_g){
  __shared__ int hist[HW_MAX];    // 4x8-bit counters/word (max in-degree ~35 << 255)
  const int HW=(N+3)>>2;
  const int tid=threadIdx.x;
  // zero control words + nmid (consumers are all in LATER dispatches — no race)
  if(blockIdx.x==0 && tid<12) ctrl[tid]=0;
  for(int i=blockIdx.x*1024+tid;i<CAP_T*80;i+=NBH*1024) nmid_g[i]=0.f;
  for(int w=tid;w<HW;w+=1024) hist[w]=0;
  __syncthreads();
  int nQ=(E+3)>>2;
  for(int q=blockIdx.x*1024+tid;q<nQ;q+=NBH*1024){
    int e=q*4;
    if(e+3<E){
      int4 v=*reinterpret_cast<const int4*>(eto+e);
      atomicAdd(&hist[v.x>>2], 1<<((v.x&3)*8));
      atomicAdd(&hist[v.y>>2], 1<<((v.y&3)*8));
      atomicAdd(&hist[v.z>>2], 1<<((v.z&3)*8));
      atomicAdd(&hist[v.w>>2], 1<<((v.w&3)*8));
    } else {
      for(;e<E;e++){ int t=eto[e]; atomicAdd(&hist[t>>2], 1<<((t&3)*8)); }
    }
  }
  __syncthreads();
  for(int w=tid;w<HW;w+=1024) histg[blockIdx.x*HW+w]=hist[w];   // coalesced plain stores
}

// ====================== k2: merge histograms + argmax ======================
__global__ void __launch_bounds__(256,1)
k_argmax(const int* __restrict__ histg, int N, unsigned long long* __restrict__ packed){
  const int HW=(N+3)>>2;
  int w=blockIdx.x*256+threadIdx.x;
  unsigned long long lm=0ull;
  if(w<HW){
    int c0=0,c1=0,c2=0,c3=0;
    #pragma unroll
    for(int b=0;b<NBH;b++){
      int h=histg[b*HW+w];                 // plain cached loads, coalesced
      c0+=h&255; c1+=(h>>8)&255; c2+=(h>>16)&255; c3+=(int)((unsigned)h>>24);
    }
    int node=w*4;
    if(c0>0)          lm=max(lm,(((unsigned long long)(unsigned)c0)<<32)|(unsigned long long)(0xFFFFFFFFu-(unsigned)(node  )));
    if(node+1<N&&c1>0)lm=max(lm,(((unsigned long long)(unsigned)c1)<<32)|(unsigned long long)(0xFFFFFFFFu-(unsigned)(node+1)));
    if(node+2<N&&c2>0)lm=max(lm,(((unsigned long long)(unsigned)c2)<<32)|(unsigned long long)(0xFFFFFFFFu-(unsigned)(node+2)));
    if(node+3<N&&c3>0)lm=max(lm,(((unsigned long long)(unsigned)c3)<<32)|(unsigned long long)(0xFFFFFFFFu-(unsigned)(node+3)));
  }
  #pragma unroll
  for(int off=32;off;off>>=1){
    unsigned long long o=__shfl_xor(lm,off);
    lm=max(lm,o);
  }
  if((threadIdx.x&63)==0 && lm) atomicMax(packed,lm);
}

// ====================== k3: collect edges out of Co ======================
__global__ void __launch_bounds__(256,1)
k_collect(const int* __restrict__ efrom, int E,
          const unsigned long long* __restrict__ packed,
          int* __restrict__ S, int* __restrict__ numS){
  int co=(int)(0xFFFFFFFFu-(unsigned)((*packed)&0xFFFFFFFFull));  // numpy argmax (first max)
  int q=blockIdx.x*256+threadIdx.x;
  int e=q*4;
  if(e+3<E){
    int4 v=*reinterpret_cast<const int4*>(efrom+e);
    int f[4]={v.x,v.y,v.z,v.w};
    #pragma unroll
    for(int k=0;k<4;k++){
      if(f[k]==co){
        int p=atomicAdd(numS,1);
        if(p<CAP_S) S[p]=e+k;
      }
    }
  } else {
    for(;e<E;e++){
      if(efrom[e]==co){
        int p=atomicAdd(numS,1);
        if(p<CAP_S) S[p]=e;
      }
    }
  }
}

// ====================== k4: scan efrom for M-edges (bitmap + slot-packed append) ======================
__global__ void __launch_bounds__(256,1)
k_scanM(const int* __restrict__ efrom, const int* __restrict__ eto, int E, int N,
        const int* __restrict__ S, const int* __restrict__ numS,
        int* __restrict__ M, int* __restrict__ numM){
  __shared__ int bitmap[BM_MAX];
  __shared__ int Te[CAP_T];
  __shared__ int Tlist[CAP_T];
  __shared__ int nTs;
  const int tid=threadIdx.x;
  int ns=*numS; if(ns>CAP_S) ns=CAP_S;
  int nsc=min(ns,CAP_T);
  const int BMW=(N+31)>>5;
  for(int w=tid;w<BMW;w+=256) bitmap[w]=0;
  if(tid<nsc) Te[tid]=eto[S[tid]];
  __syncthreads();
  if(tid<64){   // wave 0: deterministic ballot dedup + prefix slots (same order as k_tail)
    bool keep=false; int myv=0;
    if(tid<nsc){
      myv=Te[tid];
      keep=true;
      for(int k=0;k<tid;k++) if(Te[k]==myv){ keep=false; break; }
    }
    unsigned long long mask=__ballot(keep);
    if(keep){
      int slot=__popcll(mask&((1ull<<tid)-1ull));
      Tlist[slot]=myv;
    }
    if(tid==0) nTs=__popcll(mask);
  }
  __syncthreads();
  int nT=nTs;
  if(tid<nT){ int v=Tlist[tid]; atomicOr(&bitmap[v>>5], 1<<(v&31)); }
  __syncthreads();
  int q=blockIdx.x*256+tid;
  int e=q*4;
  if(e+3<E){
    int4 v=*reinterpret_cast<const int4*>(efrom+e);
    int f[4]={v.x,v.y,v.z,v.w};
    #pragma unroll
    for(int k=0;k<4;k++){
      int s=f[k];
      if((bitmap[s>>5]>>(s&31))&1){
        int sl=0;
        for(int kk=0;kk<nT;kk++) if(Tlist[kk]==s){ sl=kk; break; }
        int p=atomicAdd(numM,1);
        if(p<CAP_M) M[p]=(e+k)|(sl<<20);   // e < 2^20 (E=600k); slot in bits 20..25
      }
    }
  } else {
    for(;e<E;e++){
      int s=efrom[e];
      if((bitmap[s>>5]>>(s&31))&1){
        int sl=0;
        for(int kk=0;kk<nT;kk++) if(Tlist[kk]==s){ sl=kk; break; }
        int p=atomicAdd(numM,1);
        if(p<CAP_M) M[p]=e|(sl<<20);
      }
    }
  }
}

// ====================== k_tail: mlp (16 blocks) -> gridbar -> final (block 0) ======================
__global__ void __launch_bounds__(1024,1)
k_tail(const float* __restrict__ x, const float* __restrict__ pos,
       const int* __restrict__ efrom, const int* __restrict__ eto,
       const float* __restrict__ W1, const float* __restrict__ W2,
       const float* __restrict__ tp2,
       const int* __restrict__ S, const int* __restrict__ numS,
       const int* __restrict__ M, const int* __restrict__ numM,
       float* __restrict__ nmid_g, int* __restrict__ bars,
       W3JArg w3, float* __restrict__ out5){
  __shared__ float W1s[600], W2s[600];
  __shared__ float shs[EB*16], embs[EB*20], hs[EB*30], tws[EB*20];
  __shared__ float es_[EB], dd_[EB];
  __shared__ int   sl_[EB];
  __shared__ float w3s[675], nmid_s[CAP_T*80], tp2s[35], acc[5];
  __shared__ int   Te[CAP_T], Tlist[CAP_T], nTs;
  const int tid=threadIdx.x, bid=blockIdx.x;

  // ---- phase 1: per-M-edge radial MLP + sh -> nmid (task-parallel pipeline, all blocks) ----
  int nm=*numM; if(nm>CAP_M) nm=CAP_M;     // plain: crosses dispatch boundary only
  for(int i=tid;i<600;i+=1024){ W1s[i]=W1[i]; W2s[i]=W2[i]; }
  int per=(nm+NB2-1)/NB2;
  int lo=min(nm,bid*per), hi=min(nm,lo+per);
  for(int base=lo;base<hi;base+=EB){
    int cnt=min(EB,hi-base);
    __syncthreads();            // W1s ready (1st iter) + LDS reuse across batches
    if(tid<cnt){
      int m=M[base+tid];
      int e=m&0xFFFFF, sl=m>>20;
      sl_[tid]=sl;
      int a=efrom[e], b=eto[e];
      float dx=pos[3*b]-pos[3*a], dy=pos[3*b+1]-pos[3*a+1], dz=pos[3*b+2]-pos[3*a+2];
      float d=sqrtf(dx*dx+dy*dy+dz*dz);
      float inv=1.f/d;
      calc_sh(dx*inv,dy*inv,dz*inv,&shs[tid*16]);
      dd_[tid]=d;
      es_[tid]=x[b]*(0.18257418583505536f*0.4082482904638631f); // 1/sqrt30 * 1/sqrt6
    }
    __syncthreads();
    for(int t=tid;t<cnt*20;t+=1024){      // radial embedding
      int ee=t/20, i=t-ee*20;
      const float inv_step=21.f/3.5f;
      const float pref=(float)(1.14136*7.3890560989306495);  // 1.14136*e^2
      float di=dd_[ee]*inv_step;
      float A=di-(float)i, B=(float)(i+2)-di;
      float ua=(A>0.f)?expf(-1.f/A):0.f;
      float ub=(B>0.f)?expf(-1.f/B):0.f;
      embs[ee*20+i]=pref*ua*ub;
    }
    __syncthreads();
    for(int t=tid;t<cnt*30;t+=1024){      // MLP layer 1
      int ee=t/30, j=t-ee*30;
      float z=0.f;
      #pragma unroll
      for(int i=0;i<20;i++) z+=embs[ee*20+i]*W1s[i*30+j];
      z*=0.22360679774997896f;                  // 1/sqrt20
      hs[ee*30+j]=1.679177f*z/(1.f+expf(-z));   // NORM2MOM * silu
    }
    __syncthreads();
    for(int t=tid;t<cnt*20;t+=1024){      // MLP layer 2
      int ee=t/20, c=t-ee*20;
      float v=0.f;
      #pragma unroll
      for(int j=0;j<30;j++) v+=hs[ee*30+j]*W2s[j*20+c];
      tws[ee*20+c]=v;
    }
    __syncthreads();
    for(int t=tid;t<cnt*80;t+=1024){      // mid accumulation (device-scope atomics = coherent)
      int ee=t/80, oo=t-ee*80;
      int sl=sl_[ee];
      int l,u,mm;
      if(oo<5){ l=0; u=oo; mm=0; }
      else if(oo<20){ int r=oo-5;  l=1; u=r/3; mm=r-u*3; }
      else if(oo<45){ int r=oo-20; l=2; u=r/5; mm=r-u*5; }
      else          { int r=oo-45; l=3; u=r/7; mm=r-u*7; }
      float val=es_[ee]*tws[ee*20+l*5+u]*shs[ee*16+l*l+mm];
      atomicAdd(&nmid_g[sl*80+oo],val);
    }
  }
  gridbar(&bars[0],NB2);
  if(bid!=0) return;

  // ---- phase 2: second tensor product + output (block 0 only) ----
  for(int i=tid;i<675;i+=1024) w3s[i]=w3.w[i];
  if(tid<35) tp2s[tid]=tp2[tid];
  if(tid<5) acc[tid]=0.f;
  int ns=*numS; if(ns>CAP_S) ns=CAP_S;
  int nsc=min(ns,CAP_T);
  if(tid<nsc) Te[tid]=eto[S[tid]];
  __syncthreads();
  if(tid<64){   // identical dedup order as k_scanM -> identical slots
    bool keep=false; int myv=0;
    if(tid<nsc){
      myv=Te[tid];
      keep=true;
      for(int k=0;k<tid;k++) if(Te[k]==myv){ keep=false; break; }
    }
    unsigned long long mask=__ballot(keep);
    if(keep){
      int slot=__popcll(mask&((1ull<<tid)-1ull));
      Tlist[slot]=myv;
    }
    if(tid==0) nTs=__popcll(mask);
  }
  __syncthreads();
  int nT=nTs;
  for(int i=tid;i<nT*80;i+=1024) nmid_s[i]=cloadf(&nmid_g[i]);  // coherent: written pre-barrier by other blocks
  for(int base=0;base<ns;base+=EB){
    int cnt=min(EB,ns-base);
    __syncthreads();
    if(tid<cnt){
      int e=S[base+tid];
      int a=efrom[e], b=eto[e];
      int sl=-1;
      for(int k=0;k<nT;k++) if(Tlist[k]==b){ sl=k; break; }
      sl_[tid]=sl;
      if(sl>=0){
        float dx=pos[3*b]-pos[3*a], dy=pos[3*b+1]-pos[3*a+1], dz=pos[3*b+2]-pos[3*a+2];
        float d=sqrtf(dx*dx+dy*dy+dz*dz);
        float inv=1.f/d;
        calc_sh(dx*inv,dy*inv,dz*inv,&shs[tid*16]);
      }
    }
    __syncthreads();
    for(int t=tid;t<cnt*35;t+=1024){
      int ee=t/35, r=t-ee*35, p=r/5, u=r-p*5;
      int sl=sl_[ee];
      if(sl>=0){
        int l1=(p+1)>>1;                         // 0,1,1,2,2,3,3
        int l2=(0x3636>>(2*p))&3;                // 2,1,3,0,2,1,3
        const unsigned long long wbpack=
          (25ULL<<9)|(70ULL<<18)|(175ULL<<27)|(200ULL<<36)|(325ULL<<45)|(430ULL<<54);
        int wb=(int)((wbpack>>(9*p))&511ULL);    // 0,25,70,175,200,325,430
        int n1=2*l1+1, n2=2*l2+1;
        float tu=tp2s[p*5+u];
        float o0=0.f,o1=0.f,o2=0.f,o3=0.f,o4=0.f;
        const float* mrow=&nmid_s[sl*80+5*l1*l1+u*n1];
        const float* shrow=&shs[ee*16+l2*l2];
        const float* Wp=&w3s[wb];
        for(int i=0;i<n1;i++){
          float mi=mrow[i]*tu;
          for(int j=0;j<n2;j++){
            float c=mi*shrow[j];
            const float* Wk=Wp+(i*n2+j)*5;
            o0+=Wk[0]*c; o1+=Wk[1]*c; o2+=Wk[2]*c; o3+=Wk[3]*c; o4+=Wk[4]*c;
          }
        }
        atomicAdd(&acc[0],o0); atomicAdd(&acc[1],o1); atomicAdd(&acc[2],o2);
        atomicAdd(&acc[3],o3); atomicAdd(&acc[4],o4);
      }
    }
    __syncthreads();
  }
  __syncthreads();
  const float scale=0.37796447300922725f*0.4082482904638631f;  // ALPHA2 * 1/sqrt(6)
  if(tid<5) out5[tid]=acc[tid]*scale;
}

// ====================== launch ======================
extern "C" void kernel_launch(void* const* d_in, const int* in_sizes, int n_in,
                              void* d_out, int out_size, void* d_ws, size_t ws_size,
                              hipStream_t stream){
  const float* x    =(const float*)d_in[0];
  const float* pos  =(const float*)d_in[1];
  const int*   efrom=(const int*)  d_in[2];
  const int*   eto  =(const int*)  d_in[3];
  const float* W1   =(const float*)d_in[4];
  const float* W2   =(const float*)d_in[5];
  const float* tp2  =(const float*)d_in[6];
  int N=in_sizes[0], E=in_sizes[2];
  int HW=(N+3)>>2;

  char* ws=(char*)d_ws;
  size_t o=0;
  int* ctrl=(int*)(ws+o);                   // 12 ints: packed(2), numS, numM, bars(8)
  unsigned long long* packed=(unsigned long long*)(ws+o); o+=8;
  int* numS=(int*)(ws+o);                   o+=4;
  int* numM=(int*)(ws+o);                   o+=4;
  int* bars=(int*)(ws+o);                   o+=8*4;
  o=(o+63)&~(size_t)63;
  int* histg=(int*)(ws+o);                  o+=(size_t)NBH*HW*4;   // 1.6 MB, fully overwritten by k1
  int* S=(int*)(ws+o);                      o+=(size_t)CAP_S*4;
  int* M=(int*)(ws+o);                      o+=(size_t)CAP_M*4;
  float* nmid_g=(float*)(ws+o);             o+=(size_t)CAP_T*80*4; // zeroed in k_hist

  int nQ=(E+3)>>2;
  int gScan=(nQ+255)/256;
  int gArg =(HW+255)/256;
  k_hist   <<<NBH,1024,0,stream>>>(eto,E,N,histg,ctrl,nmid_g);
  k_argmax <<<gArg,256,0,stream>>>(histg,N,packed);
  k_collect<<<gScan,256,0,stream>>>(efrom,E,packed,S,numS);
  k_scanM  <<<gScan,256,0,stream>>>(efrom,eto,E,N,S,numS,M,numM);
  k_tail   <<<NB2,1024,0,stream>>>(x,pos,efrom,eto,W1,W2,tp2,S,numS,M,numM,nmid_g,bars,g_w3j,(float*)d_out);
}